// Round 13
// baseline (110.357 us; speedup 1.0000x reference)
//
#include <hip/hip_runtime.h>
#include <hip/hip_bf16.h>
#include <cstdint>

#define BATCH 8192
#define DIM   128
#define KAUG  160          // 128 data + 10 label dims + 22 zero pad
#define MARGIN 1.0f
#define SEP    8192.0f     // 2 * 64^2 label separator (exact in fp32/bf16)

typedef __attribute__((ext_vector_type(8))) short short8;
typedef __attribute__((ext_vector_type(4))) float f32x4;

// ---------------------------------------------------------------------------
// Kernel 1: build label-AUGMENTED bf16 matrices (validated R10-R12, absmax 0):
//   EbfA row i: [bf16(e_i), +64*onehot(lab_i), 0...]   (160 dims)
//   EbfB row j: [bf16(e_j), -64*onehot(lab_j), 0...]
//   val = sq_j - 2*dot_aug = (sq_j - 2*dot) + 8192*[same]: label selection
//   is pure max/min in the epilogue (3 VALU/pair, no label loads).
// ---------------------------------------------------------------------------
__global__ __launch_bounds__(256) void bhtl_prep(
    const float* __restrict__ emb,
    const int* __restrict__ labels,
    __hip_bfloat16* __restrict__ EbfA,
    __hip_bfloat16* __restrict__ EbfB,
    float* __restrict__ sq,
    unsigned* __restrict__ hp2,
    unsigned* __restrict__ hn2)
{
    const int w   = threadIdx.x >> 6;
    const int l   = threadIdx.x & 63;
    const int row = blockIdx.x * 4 + w;
    const float2 e = ((const float2*)(emb + row * DIM))[l];
    __hip_bfloat162 h2;
    h2.x = __float2bfloat16(e.x);
    h2.y = __float2bfloat16(e.y);
    ((__hip_bfloat162*)(EbfA + (size_t)row * KAUG))[l] = h2;
    ((__hip_bfloat162*)(EbfB + (size_t)row * KAUG))[l] = h2;
    if (l < 16) {   // augmented dims 128 + 2l, 129 + 2l
        const int lab = labels[row];
        const float a0 = (2 * l     == lab) ? 64.f : 0.f;
        const float a1 = (2 * l + 1 == lab) ? 64.f : 0.f;
        __hip_bfloat162 hA, hB;
        hA.x = __float2bfloat16(a0);  hA.y = __float2bfloat16(a1);
        hB.x = __float2bfloat16(-a0); hB.y = __float2bfloat16(-a1);
        ((__hip_bfloat162*)(EbfA + (size_t)row * KAUG + DIM))[l] = hA;
        ((__hip_bfloat162*)(EbfB + (size_t)row * KAUG + DIM))[l] = hB;
    }
    float s = e.x * e.x + e.y * e.y;
    #pragma unroll
    for (int d = 1; d < 64; d <<= 1) s += __shfl_xor(s, d, 64);
    if (l == 0) {
        sq[row]  = s;
        hp2[row] = 0u;           // max accumulator (clamped non-negative)
        hn2[row] = 0x7F800000u;  // +inf (min accumulator)
    }
}

// ---------------------------------------------------------------------------
// Kernel 2: fused augmented E_A @ E_B^T + max/min epilogue.
// HIGH-OCCUPANCY, ZERO-LDS, REGISTER-DOUBLE-BUFFERED, fully independent
// waves (the one corner of the design space R2/R3/R4 each missed):
//   4096 blocks x 64 threads = 4096 waves. Wave = block (no barriers ever).
//   Wave: 32 rows x 512 cols, K=160, in 32 chunks of 16 cols.
//   Register census ~112 < 128 -> __launch_bounds__(64, 4): 4 waves/SIMD,
//   16 waves/CU (double any LDS design's TLP; LDS caps at 8).
//   B fragments double-buffered in REGISTERS: loads for chunk k+1 issue
//   before compute of chunk k; compiler's precise per-register vmcnt leaves
//   next chunk's 5 loads outstanding across each compute block.
//   af pinned via asm "+v" (forces VGPR class too -> no R4 AGPR shunt).
//   L1 locality: js = bid & 15 -> all blocks co-resident on a CU (bids
//   congruent mod 256, hence mod 16) sweep the SAME columns -> B stream is
//   L1-multicast, L2 traffic ~2.6 MB/XCD.
// Transposed MFMA (validated R4-R12): acc = mfma(B, A); lane (q,ln) elem r
//   -> row = rowbase + m*16 + ln, col = jb + q*4 + r.
// Atomics fire-and-forget, NO fence (R5 lesson).
// ---------------------------------------------------------------------------
__global__ __launch_bounds__(64, 4) void bhtl_main(
    const __hip_bfloat16* __restrict__ EbfA,
    const __hip_bfloat16* __restrict__ EbfB,
    const float* __restrict__ sq,
    unsigned* __restrict__ hp2,
    unsigned* __restrict__ hn2)
{
    const int lane = threadIdx.x;          // 0..63
    const int q    = lane >> 4;
    const int ln   = lane & 15;
    const int bid  = blockIdx.x;
    const int js   = bid & 15;             // col split: shared by co-resident blocks
    const int rb   = bid >> 4;             // 0..255 row band (32 rows)
    const int rowbase = rb * 32;
    const int jbase   = js * 512;

    // ---- A fragments (32 rows, K=160) pinned in 40 VGPRs + row sq ----
    short8 af[2][5];
    float  sqi[2];
    #pragma unroll
    for (int m = 0; m < 2; ++m) {
        const int row = rowbase + m * 16 + ln;
        #pragma unroll
        for (int kc = 0; kc < 5; ++kc) {
            af[m][kc] = *(const short8*)(EbfA + (size_t)row * KAUG + kc * 32 + q * 8);
            asm("" : "+v"(af[m][kc]));     // pin: no re-sink (R2), no AGPR (R4)
        }
        sqi[m] = sq[row];
    }

    float mp[2] = {-INFINITY, -INFINITY};
    float mn[2] = { INFINITY,  INFINITY};

    // B loader: 16 cols x K=160 -> 5 b128 per lane + col sq (L1-hot)
    auto loadB = [&](short8 (&bf)[5], f32x4& sj, int ch) {
        const int jb = jbase + ch * 16;
        #pragma unroll
        for (int kc = 0; kc < 5; ++kc)
            bf[kc] = *(const short8*)(EbfB + (size_t)(jb + ln) * KAUG + kc * 32 + q * 8);
        sj = *(const f32x4*)(sq + jb + q * 4);
    };

    auto compute = [&](const short8 (&bf)[5], const f32x4& sj) {
        f32x4 acc[2];
        const f32x4 zero = {0.f, 0.f, 0.f, 0.f};
        acc[0] = zero; acc[1] = zero;
        #pragma unroll
        for (int kc = 0; kc < 5; ++kc)
            #pragma unroll
            for (int m = 0; m < 2; ++m)
                acc[m] = __builtin_amdgcn_mfma_f32_16x16x32_bf16(
                    bf[kc], af[m][kc], acc[m], 0, 0, 0);   // transposed
        #pragma unroll
        for (int m = 0; m < 2; ++m)
            #pragma unroll
            for (int r = 0; r < 4; ++r) {
                float val = fmaf(-2.0f, acc[m][r], sj[r]);
                mp[m] = fmaxf(mp[m], val);
                mn[m] = fminf(mn[m], val);
            }
    };

    // ---- register-double-buffered sweep: 32 chunks of 16 cols ----
    short8 b0[5], b1[5];
    f32x4  s0, s1;
    loadB(b0, s0, 0);
    #pragma unroll 1
    for (int ch = 0; ch < 32; ch += 2) {
        loadB(b1, s1, ch + 1);             // prefetch odd chunk
        compute(b0, s0);                   // compute even (waits only on b0)
        if (ch + 2 < 32) loadB(b0, s0, ch + 2);   // prefetch next even
        compute(b1, s1);                   // compute odd
    }

    // ---- reduce over the 4 q-lanes sharing each row, then atomics ----
    #pragma unroll
    for (int m = 0; m < 2; ++m) {
        float a = mp[m], b = mn[m];
        a = fmaxf(a, __shfl_xor(a, 16, 64));
        a = fmaxf(a, __shfl_xor(a, 32, 64));
        b = fminf(b, __shfl_xor(b, 16, 64));
        b = fminf(b, __shfl_xor(b, 32, 64));
        if (q == 0) {
            const int row = rowbase + m * 16 + ln;
            // hp^2 = sqi + max - SEP; hn^2 = sqi + min; clamp>=0 (uint order
            // == float order; splits w/o same-class col self-correct to 0)
            atomicMax(&hp2[row], __float_as_uint(fmaxf(sqi[m] + a - SEP, 0.0f)));
            atomicMin(&hn2[row], __float_as_uint(fmaxf(sqi[m] + b, 0.0f)));
        }
    }
}

// ---------------------------------------------------------------------------
// Kernel 3: per-anchor loss + mean. Single block, deterministic output.
// ---------------------------------------------------------------------------
__global__ __launch_bounds__(1024) void bhtl_final(
    const unsigned* __restrict__ hp2,
    const unsigned* __restrict__ hn2,
    float* __restrict__ out)
{
    __shared__ float red[16];
    float sum = 0.f;
    for (int i = threadIdx.x; i < BATCH; i += 1024) {
        float hp = sqrtf(__uint_as_float(hp2[i]));
        float hn = sqrtf(__uint_as_float(hn2[i]));
        sum += fmaxf(hp - hn + MARGIN, 0.f);
    }
    #pragma unroll
    for (int d = 1; d < 64; d <<= 1) sum += __shfl_xor(sum, d, 64);
    int wv = threadIdx.x >> 6;
    if ((threadIdx.x & 63) == 0) red[wv] = sum;
    __syncthreads();
    if (threadIdx.x < 64) {
        float v = (threadIdx.x < 16) ? red[threadIdx.x] : 0.f;
        #pragma unroll
        for (int d = 1; d < 16; d <<= 1) v += __shfl_xor(v, d, 64);
        if (threadIdx.x == 0) out[0] = v / (float)BATCH;
    }
}

// ---------------------------------------------------------------------------
extern "C" void kernel_launch(void* const* d_in, const int* in_sizes, int n_in,
                              void* d_out, int out_size, void* d_ws, size_t ws_size,
                              hipStream_t stream)
{
    const float* emb    = (const float*)d_in[0];
    const int*   labels = (const int*)d_in[1];
    float*       out    = (float*)d_out;

    char* ws = (char*)d_ws;
    __hip_bfloat16* EbfA = (__hip_bfloat16*)ws;                       // 2.56 MiB
    __hip_bfloat16* EbfB = (__hip_bfloat16*)(ws + 3  * 1024 * 1024);  // 2.56 MiB
    float*    sq   = (float*)   (ws + 6 * 1024 * 1024);               // 32 KiB
    unsigned* hp2  = (unsigned*)(ws + 6 * 1024 * 1024 + 32 * 1024);   // 32 KiB
    unsigned* hn2  = (unsigned*)(ws + 6 * 1024 * 1024 + 64 * 1024);   // 32 KiB

    bhtl_prep<<<BATCH / 4, 256, 0, stream>>>(emb, labels, EbfA, EbfB, sq, hp2, hn2);
    bhtl_main<<<4096, 64, 0, stream>>>(EbfA, EbfB, sq, hp2, hn2);
    bhtl_final<<<1, 1024, 0, stream>>>(hp2, hn2, out);
}

// Round 14
// 87.356 us; speedup vs baseline: 1.2633x; 1.2633x over previous
//
#include <hip/hip_runtime.h>
#include <hip/hip_bf16.h>
#include <cstdint>

#define BATCH 8192
#define DIM   128
#define KAUG  160          // 128 data + 10 label dims + 22 zero pad
#define MARGIN 1.0f
#define SEP    8192.0f     // 2 * 64^2 label separator (exact in fp32/bf16)

typedef __attribute__((ext_vector_type(8))) short short8;
typedef __attribute__((ext_vector_type(4))) float f32x4;

// async 16B global -> LDS; LDS dst = wave-uniform base, HW adds lane*16
__device__ __forceinline__ void async_copy16(const void* g, void* lds) {
    __builtin_amdgcn_global_load_lds(
        (const __attribute__((address_space(1))) unsigned int*)g,
        (__attribute__((address_space(3))) unsigned int*)lds, 16, 0, 0);
}

// ---------------------------------------------------------------------------
// Kernel 1: build label-AUGMENTED bf16 matrices (validated R10-R13, absmax 0):
//   EbfA row i: [bf16(e_i), +64*onehot(lab_i), 0...]   (160 dims)
//   EbfB row j: [bf16(e_j), -64*onehot(lab_j), 0...]
//   val = sq_j - 2*dot_aug = (sq_j - 2*dot) + 8192*[same]: label selection
//   is pure max/min in the epilogue (3 VALU/pair, no label loads).
// ---------------------------------------------------------------------------
__global__ __launch_bounds__(256) void bhtl_prep(
    const float* __restrict__ emb,
    const int* __restrict__ labels,
    __hip_bfloat16* __restrict__ EbfA,
    __hip_bfloat16* __restrict__ EbfB,
    float* __restrict__ sq,
    unsigned* __restrict__ hp2,
    unsigned* __restrict__ hn2)
{
    const int w   = threadIdx.x >> 6;
    const int l   = threadIdx.x & 63;
    const int row = blockIdx.x * 4 + w;
    const float2 e = ((const float2*)(emb + row * DIM))[l];
    __hip_bfloat162 h2;
    h2.x = __float2bfloat16(e.x);
    h2.y = __float2bfloat16(e.y);
    ((__hip_bfloat162*)(EbfA + (size_t)row * KAUG))[l] = h2;
    ((__hip_bfloat162*)(EbfB + (size_t)row * KAUG))[l] = h2;
    if (l < 16) {   // augmented dims 128 + 2l, 129 + 2l
        const int lab = labels[row];
        const float a0 = (2 * l     == lab) ? 64.f : 0.f;
        const float a1 = (2 * l + 1 == lab) ? 64.f : 0.f;
        __hip_bfloat162 hA, hB;
        hA.x = __float2bfloat16(a0);  hA.y = __float2bfloat16(a1);
        hB.x = __float2bfloat16(-a0); hB.y = __float2bfloat16(-a1);
        ((__hip_bfloat162*)(EbfA + (size_t)row * KAUG + DIM))[l] = hA;
        ((__hip_bfloat162*)(EbfB + (size_t)row * KAUG + DIM))[l] = hB;
    }
    float s = e.x * e.x + e.y * e.y;
    #pragma unroll
    for (int d = 1; d < 64; d <<= 1) s += __shfl_xor(s, d, 64);
    if (l == 0) {
        sq[row]  = s;
        hp2[row] = 0u;           // max accumulator (clamped non-negative)
        hn2[row] = 0x7F800000u;  // +inf (min accumulator)
    }
}

// ---------------------------------------------------------------------------
// Kernel 2: fused augmented E_A @ E_B^T + max/min epilogue.
// EXACTLY the R10 structure (best measured: wave-private glds staging,
// zero barriers, 16-col chunks, depth-2 prefetch via 3 buffers, explicit
// vmcnt(5)/vmcnt(0) discipline, aug epilogue) — but as SINGLE-WAVE blocks:
//   2048 blocks x 64 threads; wave = 64 rows x 512 cols, 32 chunks.
//   LDS grain 17.4 KB/block -> 9 blocks/CU (vs R10's 4x128-thr = 8 waves);
//   VGPR census ~168 <= 170 -> SIMDs can host 3 waves (9/CU, mixed 3/2).
//   Same recipe, +12% TLP, finer tail granularity. Downside bounded: if
//   VGPR lands > 170 the scheduler gives 8 waves/CU == R10 exactly.
// XOR swizzle on global side, transposed MFMA (lane(q,ln) elem r ->
//   row = rowbase+m*16+ln, col = jb+q*4+r) — both validated R4-R13.
// Atomics fire-and-forget, NO fence (R5 lesson).
// ---------------------------------------------------------------------------
__global__ __launch_bounds__(64) void bhtl_main(
    const __hip_bfloat16* __restrict__ EbfA,
    const __hip_bfloat16* __restrict__ EbfB,
    const float* __restrict__ sq,
    unsigned* __restrict__ hp2,
    unsigned* __restrict__ hn2)
{
    __shared__ __align__(16) unsigned short B_s[3][2560];  // 3 bufs x 5 KB
    __shared__ __align__(16) float sqm[512];               // col sq (2 KB)

    const int lane = threadIdx.x;              // 0..63
    const int q    = lane >> 4;
    const int ln   = lane & 15;
    const int rb   = blockIdx.x >> 4;          // 0..127 row band (64 rows)
    const int js   = blockIdx.x & 15;          // 0..15 col split (512 cols)
    const int rowbase = rb * 64;
    const int jbase   = js * 512;

    // ---- A fragments (64 rows, K=160), pinned in 80 VGPRs ----
    short8 af[4][5];
    #pragma unroll
    for (int m = 0; m < 4; ++m)
        #pragma unroll
        for (int kc = 0; kc < 5; ++kc) {
            af[m][kc] = *(const short8*)(
                EbfA + (size_t)(rowbase + m * 16 + ln) * KAUG + kc * 32 + q * 8);
            asm("" : "+v"(af[m][kc]));
        }

    // ---- stage col sq (512 floats = 2 KB = 2 glds) ----
    #pragma unroll
    for (int c = 0; c < 2; ++c)
        async_copy16(sq + jbase + (c * 64 + lane) * 4, &sqm[c * 256]);

    // drain prologue vmem (af VGPR loads + meta glds) before counted pipeline
    asm volatile("s_waitcnt vmcnt(0)" ::: "memory");

    // ---- B chunk stager: 16 cols x 320 B = 320 units = 5 glds ----
    auto stageB = [&](int buf, int ch) {
        const int jb = jbase + ch * 16;
        #pragma unroll
        for (int c = 0; c < 5; ++c) {
            int U   = c * 64 + lane;           // 0..319
            int col = U / 20;                  // 0..15 (magic-mul)
            int u   = U - col * 20;            // 0..19
            int g   = (u < 16) ? (u ^ (col & 7)) : u;   // global-side swizzle
            async_copy16(EbfB + (size_t)(jb + col) * KAUG + g * 8,
                         &B_s[buf][c * 512]);
        }
    };

    float mp[4] = {-INFINITY, -INFINITY, -INFINITY, -INFINITY};
    float mn[4] = { INFINITY,  INFINITY,  INFINITY,  INFINITY};

    auto doIter = [&](int ch, int buf, bool doStage, int stageBuf, bool last) {
        if (last) asm volatile("s_waitcnt vmcnt(0)" ::: "memory");
        else      asm volatile("s_waitcnt vmcnt(5)" ::: "memory");

        // LDS reads for chunk ch
        short8 bfr[5];
        #pragma unroll
        for (int kc = 0; kc < 5; ++kc) {
            const int t    = kc * 4 + q;                       // global unit
            const int unit = (kc < 4) ? (t ^ (ln & 7)) : t;    // stored unit
            bfr[kc] = *(const short8*)(&B_s[buf][(ln * 20 + unit) * 8]);
        }
        f32x4 sqj = *(const f32x4*)(&sqm[ch * 16 + q * 4]);

        // prefetch chunk ch+2 (depth-2)
        if (doStage) stageB(stageBuf, ch + 2);

        // MFMA: 4 row-blocks x K=160
        f32x4 acc[4];
        const f32x4 zero = {0.f, 0.f, 0.f, 0.f};
        #pragma unroll
        for (int m = 0; m < 4; ++m) acc[m] = zero;
        #pragma unroll
        for (int kc = 0; kc < 5; ++kc)
            #pragma unroll
            for (int m = 0; m < 4; ++m)
                acc[m] = __builtin_amdgcn_mfma_f32_16x16x32_bf16(
                    bfr[kc], af[m][kc], acc[m], 0, 0, 0);      // transposed

        // epilogue: 3 VALU/pair (label logic inside the dot)
        #pragma unroll
        for (int m = 0; m < 4; ++m)
            #pragma unroll
            for (int r = 0; r < 4; ++r) {
                float val = fmaf(-2.0f, acc[m][r], sqj[r]);
                mp[m] = fmaxf(mp[m], val);
                mn[m] = fminf(mn[m], val);
            }
    };

    stageB(0, 0);
    stageB(1, 1);

    #pragma unroll 1
    for (int base = 0; base < 30; base += 3) {
        doIter(base,     0, true, 2, false);
        doIter(base + 1, 1, true, 0, false);
        doIter(base + 2, 2, base + 2 < 30, 1, false);
    }
    doIter(30, 0, false, 0, false);
    doIter(31, 1, false, 0, true);

    // ---- reduce over the 4 q-lanes sharing each row, then atomics ----
    #pragma unroll
    for (int m = 0; m < 4; ++m) {
        float a = mp[m], b = mn[m];
        a = fmaxf(a, __shfl_xor(a, 16, 64));
        a = fmaxf(a, __shfl_xor(a, 32, 64));
        b = fminf(b, __shfl_xor(b, 16, 64));
        b = fminf(b, __shfl_xor(b, 32, 64));
        if (q == 0) {
            const int row = rowbase + m * 16 + ln;
            const float sqi = sq[row];
            // hp^2 = sqi + max - SEP; hn^2 = sqi + min; clamp>=0 (uint order
            // == float order; splits w/o same-class col self-correct to 0)
            atomicMax(&hp2[row], __float_as_uint(fmaxf(sqi + a - SEP, 0.0f)));
            atomicMin(&hn2[row], __float_as_uint(fmaxf(sqi + b, 0.0f)));
        }
    }
}

// ---------------------------------------------------------------------------
// Kernel 3: per-anchor loss + mean. Single block, deterministic output.
// ---------------------------------------------------------------------------
__global__ __launch_bounds__(1024) void bhtl_final(
    const unsigned* __restrict__ hp2,
    const unsigned* __restrict__ hn2,
    float* __restrict__ out)
{
    __shared__ float red[16];
    float sum = 0.f;
    for (int i = threadIdx.x; i < BATCH; i += 1024) {
        float hp = sqrtf(__uint_as_float(hp2[i]));
        float hn = sqrtf(__uint_as_float(hn2[i]));
        sum += fmaxf(hp - hn + MARGIN, 0.f);
    }
    #pragma unroll
    for (int d = 1; d < 64; d <<= 1) sum += __shfl_xor(sum, d, 64);
    int wv = threadIdx.x >> 6;
    if ((threadIdx.x & 63) == 0) red[wv] = sum;
    __syncthreads();
    if (threadIdx.x < 64) {
        float v = (threadIdx.x < 16) ? red[threadIdx.x] : 0.f;
        #pragma unroll
        for (int d = 1; d < 16; d <<= 1) v += __shfl_xor(v, d, 64);
        if (threadIdx.x == 0) out[0] = v / (float)BATCH;
    }
}

// ---------------------------------------------------------------------------
extern "C" void kernel_launch(void* const* d_in, const int* in_sizes, int n_in,
                              void* d_out, int out_size, void* d_ws, size_t ws_size,
                              hipStream_t stream)
{
    const float* emb    = (const float*)d_in[0];
    const int*   labels = (const int*)d_in[1];
    float*       out    = (float*)d_out;

    char* ws = (char*)d_ws;
    __hip_bfloat16* EbfA = (__hip_bfloat16*)ws;                       // 2.56 MiB
    __hip_bfloat16* EbfB = (__hip_bfloat16*)(ws + 3  * 1024 * 1024);  // 2.56 MiB
    float*    sq   = (float*)   (ws + 6 * 1024 * 1024);               // 32 KiB
    unsigned* hp2  = (unsigned*)(ws + 6 * 1024 * 1024 + 32 * 1024);   // 32 KiB
    unsigned* hn2  = (unsigned*)(ws + 6 * 1024 * 1024 + 64 * 1024);   // 32 KiB

    bhtl_prep<<<BATCH / 4, 256, 0, stream>>>(emb, labels, EbfA, EbfB, sq, hp2, hn2);
    bhtl_main<<<2048, 64, 0, stream>>>(EbfA, EbfB, sq, hp2, hn2);
    bhtl_final<<<1, 1024, 0, stream>>>(hp2, hn2, out);
}

// Round 15
// 81.020 us; speedup vs baseline: 1.3621x; 1.0782x over previous
//
#include <hip/hip_runtime.h>
#include <hip/hip_bf16.h>
#include <cstdint>

#define BATCH 8192
#define DIM   128
#define KBYTES 192         // 128 data i8 + 60 label bytes + 4 pad (K=192)
#define MARGIN 1.0f
#define SEPI   193548      // 2 * 6 * 127 * 127 label separator (int, exact)
#define SCALE  16.0f       // fp32 -> i8 quantization scale
#define INVS2  (1.0f / 256.0f)

typedef __attribute__((ext_vector_type(4))) int   int4v;
typedef __attribute__((ext_vector_type(4))) float f32x4;

// async 16B global -> LDS; LDS dst = wave-uniform base, HW adds lane*16
__device__ __forceinline__ void async_copy16(const void* g, void* lds) {
    __builtin_amdgcn_global_load_lds(
        (const __attribute__((address_space(1))) unsigned int*)g,
        (__attribute__((address_space(3))) unsigned int*)lds, 16, 0, 0);
}

// ---------------------------------------------------------------------------
// Kernel 1: quantize fp32 -> i8 (scale 16, clamp +-127) into label-AUGMENTED
// matrices. Row (192 B): [128 data i8][60 aug: label lab -> bytes 6*lab..
// 6*lab+5 = +127 (A) / -127 (B)][4 zero pad]. dot_aug = dot - 96774*[same];
// val = sqj - 2*dot_aug = (sqj - 2*dot) + 193548*[same] -> pure max/min
// epilogue in EXACT i32 (everything < 2^24, float conversion exact).
// Also per-row integer squared norms + hp2/hn2 init.
// 8 rows/block: each 32-lane half-wave quantizes one row.
// ---------------------------------------------------------------------------
__global__ __launch_bounds__(256) void bhtl_prep(
    const float* __restrict__ emb,
    const int* __restrict__ labels,
    signed char* __restrict__ EA,
    signed char* __restrict__ EB,
    int* __restrict__ sq,
    unsigned* __restrict__ hp2,
    unsigned* __restrict__ hn2)
{
    const int hw  = threadIdx.x >> 5;          // half-wave 0..7
    const int l   = threadIdx.x & 31;
    const int row = blockIdx.x * 8 + hw;
    const float4 e = ((const float4*)(emb + (size_t)row * DIM))[l];

    int a0 = (int)rintf(e.x * SCALE); a0 = min(127, max(-127, a0));
    int a1 = (int)rintf(e.y * SCALE); a1 = min(127, max(-127, a1));
    int a2 = (int)rintf(e.z * SCALE); a2 = min(127, max(-127, a2));
    int a3 = (int)rintf(e.w * SCALE); a3 = min(127, max(-127, a3));
    unsigned pa = (a0 & 255) | ((a1 & 255) << 8) | ((a2 & 255) << 16) | ((a3 & 255) << 24);
    *(unsigned*)(EA + (size_t)row * KBYTES + l * 4) = pa;
    *(unsigned*)(EB + (size_t)row * KBYTES + l * 4) = pa;   // data identical

    if (l < 16) {   // aug bytes 128..191: 4 bytes per lane
        const int lab = labels[row];
        unsigned wa = 0, wb = 0;
        #pragma unroll
        for (int b = 0; b < 4; ++b) {
            int j = l * 4 + b;                 // 0..63
            int in = (j < 60) && (j / 6 == lab);
            wa |= (unsigned)((in ?  127 : 0) & 255) << (8 * b);
            wb |= (unsigned)((in ? -127 : 0) & 255) << (8 * b);
        }
        *(unsigned*)(EA + (size_t)row * KBYTES + 128 + l * 4) = wa;
        *(unsigned*)(EB + (size_t)row * KBYTES + 128 + l * 4) = wb;
    }

    int s = a0 * a0 + a1 * a1 + a2 * a2 + a3 * a3;
    #pragma unroll
    for (int d = 1; d < 32; d <<= 1) s += __shfl_xor(s, d, 64);  // half-wave
    if (l == 0) {
        sq[row]  = s;
        hp2[row] = 0u;           // float-bits max accumulator (non-negative)
        hn2[row] = 0x7F800000u;  // +inf (min accumulator)
    }
}

// ---------------------------------------------------------------------------
// Kernel 2: fused i8 E_A @ E_B^T + int max/min epilogue.
// EXACT R14 structure (best measured) with i8 widths:
//   2048 blocks x 64 threads; wave = 64 rows x 512 cols, 32 chunks of 16.
//   Chunk = 16 cols x 192 B = 3 KB = 3 glds. 3 wave-private buffers (9 KB)
//   + col-sq (2 KB) = 11 KB LDS -> 8 blocks/CU all resident.
//   Depth-2 prefetch: iter ch waits vmcnt(3) (drains ch, leaves ch+1's 3 in
//   flight), stages ch+2. Zero barriers (R5/R9 lessons baked in).
//   MFMA: mfma_i32_16x16x64_i8, transposed (acc = mfma(B, A)): lane(q,ln)
//   elem r -> row = rowbase+m*16+ln, col = jb+q*4+r (C/D layout is shape-
//   determined, dtype-independent on gfx950). Input frag: k = q*16 + j.
// Swizzle (global side): col's 12 units: u<8 -> u^(col&7); u>=8 ->
//   8+((u-8)^(col&3)). Read unit for t=kc*4+q: t<8 -> t^(ln&7), else
//   8+(q^(ln&3)). 2-way (free) on kc=0,1; 4-way (1.58x) on kc=2 only.
// Epilogue: val = sqj - 2*acc (int, 4 VALU/pair), mp=max, mn=min.
// Atomics fire-and-forget float-bits as before (exact int->float, <2^24).
// ---------------------------------------------------------------------------
__global__ __launch_bounds__(64) void bhtl_main(
    const signed char* __restrict__ EA,
    const signed char* __restrict__ EB,
    const int* __restrict__ sq,
    unsigned* __restrict__ hp2,
    unsigned* __restrict__ hn2)
{
    __shared__ __align__(16) unsigned char B_s[3][3072];   // 3 bufs x 3 KB
    __shared__ __align__(16) int sqm[512];                 // col sq (2 KB)

    const int lane = threadIdx.x;              // 0..63
    const int q    = lane >> 4;
    const int ln   = lane & 15;
    const int rb   = blockIdx.x >> 4;          // 0..127 row band (64 rows)
    const int js   = blockIdx.x & 15;          // 0..15 col split (512 cols)
    const int rowbase = rb * 64;
    const int jbase   = js * 512;

    // ---- A fragments (64 rows, K=192) pinned: 4 m x 3 kc x 4 VGPR = 48 ----
    int4v af[4][3];
    #pragma unroll
    for (int m = 0; m < 4; ++m)
        #pragma unroll
        for (int kc = 0; kc < 3; ++kc) {
            af[m][kc] = *(const int4v*)(
                EA + (size_t)(rowbase + m * 16 + ln) * KBYTES + kc * 64 + q * 16);
            asm("" : "+v"(af[m][kc]));
        }

    // ---- stage col sq (512 ints = 2 KB = 2 glds) ----
    #pragma unroll
    for (int c = 0; c < 2; ++c)
        async_copy16(sq + jbase + (c * 64 + lane) * 4, &sqm[c * 256]);

    asm volatile("s_waitcnt vmcnt(0)" ::: "memory");   // drain prologue vmem

    // ---- B chunk stager: 16 cols x 12 units = 192 units = 3 glds ----
    auto stageB = [&](int buf, int ch) {
        const int jb = jbase + ch * 16;
        #pragma unroll
        for (int c = 0; c < 3; ++c) {
            int U   = c * 64 + lane;           // 0..191
            int col = U / 12;                  // 0..15 (magic-mul)
            int u   = U - col * 12;            // 0..11
            int g   = (u < 8) ? (u ^ (col & 7)) : (8 + ((u - 8) ^ (col & 3)));
            async_copy16(EB + (size_t)(jb + col) * KBYTES + g * 16,
                         &B_s[buf][c * 1024]);
        }
    };

    int mp[4] = {INT_MIN, INT_MIN, INT_MIN, INT_MIN};
    int mn[4] = {INT_MAX, INT_MAX, INT_MAX, INT_MAX};

    auto doIter = [&](int ch, int buf, bool doStage, int stageBuf, bool last) {
        if (last) asm volatile("s_waitcnt vmcnt(0)" ::: "memory");
        else      asm volatile("s_waitcnt vmcnt(3)" ::: "memory");

        // LDS reads for chunk ch
        int4v bfr[3];
        #pragma unroll
        for (int kc = 0; kc < 3; ++kc) {
            const int t    = kc * 4 + q;                 // global unit 0..11
            const int unit = (t < 8) ? (t ^ (ln & 7)) : (8 + (q ^ (ln & 3)));
            bfr[kc] = *(const int4v*)(&B_s[buf][(ln * 12 + unit) * 16]);
        }
        int4v sqj = *(const int4v*)(&sqm[ch * 16 + q * 4]);

        if (doStage) stageB(stageBuf, ch + 2);           // depth-2 prefetch

        // MFMA: 4 row-blocks x K=192 (3 x 16x16x64 i8)
        int4v acc[4];
        const int4v zero = {0, 0, 0, 0};
        #pragma unroll
        for (int m = 0; m < 4; ++m) acc[m] = zero;
        #pragma unroll
        for (int kc = 0; kc < 3; ++kc)
            #pragma unroll
            for (int m = 0; m < 4; ++m)
                acc[m] = __builtin_amdgcn_mfma_i32_16x16x64_i8(
                    bfr[kc], af[m][kc], acc[m], 0, 0, 0);   // transposed

        // epilogue: val = sqj - 2*dot_aug (int, exact)
        #pragma unroll
        for (int m = 0; m < 4; ++m)
            #pragma unroll
            for (int r = 0; r < 4; ++r) {
                int val = sqj[r] - 2 * acc[m][r];
                mp[m] = max(mp[m], val);
                mn[m] = min(mn[m], val);
            }
    };

    stageB(0, 0);
    stageB(1, 1);

    #pragma unroll 1
    for (int base = 0; base < 30; base += 3) {
        doIter(base,     0, true, 2, false);
        doIter(base + 1, 1, true, 0, false);
        doIter(base + 2, 2, base + 2 < 30, 1, false);
    }
    doIter(30, 0, false, 0, false);
    doIter(31, 1, false, 0, true);

    // ---- reduce over the 4 q-lanes sharing each row, then atomics ----
    #pragma unroll
    for (int m = 0; m < 4; ++m) {
        int a = mp[m], b = mn[m];
        a = max(a, __shfl_xor(a, 16, 64));
        a = max(a, __shfl_xor(a, 32, 64));
        b = min(b, __shfl_xor(b, 16, 64));
        b = min(b, __shfl_xor(b, 32, 64));
        if (q == 0) {
            const int row = rowbase + m * 16 + ln;
            const int sqi = sq[row];
            // d^2 = (sqi + val - SEPI)/256 (pos) or (sqi + val)/256 (neg);
            // ints < 2^24 -> float conversion exact; clamp>=0 keeps uint
            // order == float order; splits w/o same-class col self-correct.
            float hpf = fmaxf((float)(sqi + a - SEPI) * INVS2, 0.0f);
            float hnf = fmaxf((float)(sqi + b) * INVS2, 0.0f);
            atomicMax(&hp2[row], __float_as_uint(hpf));
            atomicMin(&hn2[row], __float_as_uint(hnf));
        }
    }
}

// ---------------------------------------------------------------------------
// Kernel 3: per-anchor loss + mean. Single block, deterministic output.
// ---------------------------------------------------------------------------
__global__ __launch_bounds__(1024) void bhtl_final(
    const unsigned* __restrict__ hp2,
    const unsigned* __restrict__ hn2,
    float* __restrict__ out)
{
    __shared__ float red[16];
    float sum = 0.f;
    for (int i = threadIdx.x; i < BATCH; i += 1024) {
        float hp = sqrtf(__uint_as_float(hp2[i]));
        float hn = sqrtf(__uint_as_float(hn2[i]));
        sum += fmaxf(hp - hn + MARGIN, 0.f);
    }
    #pragma unroll
    for (int d = 1; d < 64; d <<= 1) sum += __shfl_xor(sum, d, 64);
    int wv = threadIdx.x >> 6;
    if ((threadIdx.x & 63) == 0) red[wv] = sum;
    __syncthreads();
    if (threadIdx.x < 64) {
        float v = (threadIdx.x < 16) ? red[threadIdx.x] : 0.f;
        #pragma unroll
        for (int d = 1; d < 16; d <<= 1) v += __shfl_xor(v, d, 64);
        if (threadIdx.x == 0) out[0] = v / (float)BATCH;
    }
}

// ---------------------------------------------------------------------------
extern "C" void kernel_launch(void* const* d_in, const int* in_sizes, int n_in,
                              void* d_out, int out_size, void* d_ws, size_t ws_size,
                              hipStream_t stream)
{
    const float* emb    = (const float*)d_in[0];
    const int*   labels = (const int*)d_in[1];
    float*       out    = (float*)d_out;

    char* ws = (char*)d_ws;
    signed char* EA  = (signed char*)ws;                              // 1.5 MiB
    signed char* EB  = (signed char*)(ws + 2 * 1024 * 1024);          // 1.5 MiB
    int*      sq   = (int*)     (ws + 4 * 1024 * 1024);               // 32 KiB
    unsigned* hp2  = (unsigned*)(ws + 4 * 1024 * 1024 + 32 * 1024);   // 32 KiB
    unsigned* hn2  = (unsigned*)(ws + 4 * 1024 * 1024 + 64 * 1024);   // 32 KiB

    bhtl_prep<<<BATCH / 8, 256, 0, stream>>>(emb, labels, EA, EB, sq, hp2, hn2);
    bhtl_main<<<2048, 64, 0, stream>>>(EA, EB, sq, hp2, hn2);
    bhtl_final<<<1, 1024, 0, stream>>>(hp2, hn2, out);
}